// Round 5
// baseline (556.125 us; speedup 1.0000x reference)
//
#include <hip/hip_runtime.h>

// LSTM autoencoder: 4 layers 64->64, B=512, T=256 — fused, single barrier/tick.
//
// ROUND-4 RESTRUCTURE: 16 batches per block -> 32 blocks x 512 threads.
// Rationale (measured): MfmaUtil/VALUBusy vs bottom-up issue counts imply
// effective clock ~750 MHz (DVFS-depressed with 256 active CUs). Packing the
// MFMA N-dim with 16 batch columns (was 2) keeps per-SIMD issue identical but
// cuts chip-wide work and active CUs by 8x -> clock headroom, AND gives every
// lane 8 register-local cells (C rows q*4+r, col n=batch): no LDS gate
// redistribute (fused6's Gs) and no 16-lane concentration (fused7).
//
// Block = 16 batch elements x 4 layers. Wave w = (layer L = w>>1, mh = w&1)
// owns units [mh*32, mh*32+32), all 4 gates, all 16 batches.
// Per tick tau (layer L at t = tau-L):
//   1. B-frags: v = h_{L-1} (or x) and h_L from padded Hb plane (parity pr)
//   2. per s-tile: 16 MFMA (16x16x32 f16) -> C[g] = gates of units
//      mh*32+s*16+q*4+r, batch n; register-local epilogue, 4 cells/lane
//   3. h -> Hb[pw] via ds_write_b64; L3 stores float4 to out (coalesced)
//   4. raw s_barrier, lgkmcnt(0)-only drain (vmcnt never drained in-loop)
// Hb rows padded to 80 f16 (160 B): B-frag b128 reads spread 8 lanes per
// 4-bank group (balanced); unpadded 128 B would be 16-way.

typedef _Float16 f16x8 __attribute__((ext_vector_type(8)));
typedef _Float16 f16x4 __attribute__((ext_vector_type(4)));
typedef float    f32x4 __attribute__((ext_vector_type(4)));

#define TSEQ 256
#define NB   16          // batches per block
#define HROW 80          // padded Hb row stride in f16 (160 B, 16B-aligned)

__device__ __forceinline__ float fast_rcp(float x) { return __builtin_amdgcn_rcpf(x); }
__device__ __forceinline__ float sigm(float x) { return fast_rcp(1.0f + __expf(-x)); }
__device__ __forceinline__ float tanh_fast(float x) {
    return 2.0f * fast_rcp(1.0f + __expf(-2.0f * x)) - 1.0f;
}
__device__ __forceinline__ f16x8 cvt8(float4 a, float4 b) {
    f16x8 f;
    f[0] = (_Float16)a.x; f[1] = (_Float16)a.y; f[2] = (_Float16)a.z; f[3] = (_Float16)a.w;
    f[4] = (_Float16)b.x; f[5] = (_Float16)b.y; f[6] = (_Float16)b.z; f[7] = (_Float16)b.w;
    return f;
}

__global__ __launch_bounds__(512, 2)
void lstm_fused8(const float* __restrict__ x,     // [512, 256, 64]
                 float* __restrict__ out,         // [512, 256, 64]
                 const float* __restrict__ Wih0, const float* __restrict__ Whh0,
                 const float* __restrict__ bi0,  const float* __restrict__ bh0,
                 const float* __restrict__ Wih1, const float* __restrict__ Whh1,
                 const float* __restrict__ bi1,  const float* __restrict__ bh1,
                 const float* __restrict__ Wih2, const float* __restrict__ Whh2,
                 const float* __restrict__ bi2,  const float* __restrict__ bh2,
                 const float* __restrict__ Wih3, const float* __restrict__ Whh3,
                 const float* __restrict__ bi3,  const float* __restrict__ bh3)
{
    __shared__ _Float16 Hb[2][4][NB][HROW];   // 20480 B: parity, layer, batch, unit(padded)

    const int tid  = threadIdx.x;
    const int wave = tid >> 6;
    const int lane = tid & 63;
    const int L    = wave >> 1;     // layer 0..3
    const int mh   = wave & 1;      // unit-half: units [mh*32, mh*32+32)
    const int q    = lane >> 4;     // k-quad; also C row-group (rows q*4+r)
    const int n    = lane & 15;     // MFMA col = batch index within block
    const int b0   = blockIdx.x * NB;

    const float* Wih = (L == 0) ? Wih0 : (L == 1) ? Wih1 : (L == 2) ? Wih2 : Wih3;
    const float* Whh = (L == 0) ? Whh0 : (L == 1) ? Whh1 : (L == 2) ? Whh2 : Whh3;
    const float* bi  = (L == 0) ? bi0  : (L == 1) ? bi1  : (L == 2) ? bi2  : bi3;
    const float* bh  = (L == 0) ? bh0  : (L == 1) ? bh1  : (L == 2) ? bh2  : bh3;

    // ---- persistent W A-frags: tile (g,s) = rows g*64+mh*32+s*16+[0,16) ----
    // A[m=lane&15][k=q*8+kk]; two k-halves c=0,1 (k = c*32 + q*8 + kk)
    f16x8 Aih[4][2][2], Ahh[4][2][2];
#pragma unroll
    for (int g = 0; g < 4; ++g) {
#pragma unroll
        for (int s = 0; s < 2; ++s) {
            const int row = g * 64 + mh * 32 + s * 16 + n;
#pragma unroll
            for (int c = 0; c < 2; ++c) {
                const float* pi = Wih + row * 64 + c * 32 + q * 8;
                const float* ph = Whh + row * 64 + c * 32 + q * 8;
                f16x8 fi, fh;
#pragma unroll
                for (int k = 0; k < 8; ++k) { fi[k] = (_Float16)pi[k]; fh[k] = (_Float16)ph[k]; }
                Aih[g][s][c] = fi;
                Ahh[g][s][c] = fh;
            }
        }
    }

    // ---- epilogue identity: lane owns cells (s=0..1, r=0..3) of batch n,
    //      unit u(s,r) = mh*32 + s*16 + q*4 + r ----
    float be[2][4][4];                       // [s][g][r] gate biases (init-only loads)
#pragma unroll
    for (int s = 0; s < 2; ++s)
#pragma unroll
        for (int g = 0; g < 4; ++g)
#pragma unroll
            for (int r = 0; r < 4; ++r) {
                const int u = g * 64 + mh * 32 + s * 16 + q * 4 + r;
                be[s][g][r] = bi[u] + bh[u];
            }
    float cst[2][4] = {{0.f,0.f,0.f,0.f},{0.f,0.f,0.f,0.f}};   // [s][r], static idx only
    float* outp = out + ((size_t)(b0 + n) * TSEQ) * 64 + mh * 32 + q * 4;  // L==3 only

    // ---- zero h state (both parities): 20480 B = 5120 ints, 10 per thread ----
#pragma unroll
    for (int i = tid; i < 5120; i += 512) ((int*)Hb)[i] = 0;

    // ---- L0 x prefetch: one tick ahead, ALL lanes (batch n, k-quad q) ----
    const float* xbase = x + ((size_t)(b0 + n) * TSEQ) * 64 + q * 8;
    float4 R0, R1, R2, R3;
    R0 = R1 = R2 = R3 = make_float4(0.f, 0.f, 0.f, 0.f);
    if (L == 0) {
        R0 = *(const float4*)(xbase);      R1 = *(const float4*)(xbase + 4);
        R2 = *(const float4*)(xbase + 32); R3 = *(const float4*)(xbase + 36);
    }

    __syncthreads();

    for (int tau = 0; tau < TSEQ + 3; ++tau) {
        const int  t   = tau - L;
        const bool act = (unsigned)t < TSEQ;   // wave-uniform
        const int  pr  = (tau + 1) & 1;
        const int  pw  = tau & 1;

        if (act) {
            // ---- B-frags: B[k=q*8+kk][col=n] = activation elem k of batch n ----
            f16x8 vf0, vf1;
            if (L == 0) {
                vf0 = cvt8(R0, R1);            // x(t) elems q*8.. / 32+q*8..
                vf1 = cvt8(R2, R3);
                if (t + 1 < TSEQ) {            // prefetch x(t+1)
                    const float* p = xbase + (size_t)(t + 1) * 64;
                    R0 = *(const float4*)(p);      R1 = *(const float4*)(p + 4);
                    R2 = *(const float4*)(p + 32); R3 = *(const float4*)(p + 36);
                }
            } else {
                const _Float16* vp = &Hb[pr][L - 1][n][0];
                vf0 = *(const f16x8*)(vp + q * 8);
                vf1 = *(const f16x8*)(vp + 32 + q * 8);
            }
            const _Float16* hp = &Hb[pr][L][n][0];
            f16x8 hf0 = *(const f16x8*)(hp + q * 8);
            f16x8 hf1 = *(const f16x8*)(hp + 32 + q * 8);

            const f32x4 z4 = {0.f, 0.f, 0.f, 0.f};

            // ---- per s-tile: 16 MFMA then register-local 4-cell epilogue ----
#pragma unroll
            for (int s = 0; s < 2; ++s) {
                f32x4 C[4];
#pragma unroll
                for (int g = 0; g < 4; ++g) {
                    f32x4 c;
                    c = __builtin_amdgcn_mfma_f32_16x16x32_f16(Ahh[g][s][0], hf0, z4, 0, 0, 0);
                    c = __builtin_amdgcn_mfma_f32_16x16x32_f16(Ahh[g][s][1], hf1, c,  0, 0, 0);
                    c = __builtin_amdgcn_mfma_f32_16x16x32_f16(Aih[g][s][0], vf0, c,  0, 0, 0);
                    C[g] = __builtin_amdgcn_mfma_f32_16x16x32_f16(Aih[g][s][1], vf1, c, 0, 0, 0);
                }
                // cells r=0..3: unit mh*32+s*16+q*4+r, batch n — all in registers
                f16x4 hp4;
                float  ho0, ho1, ho2, ho3;
#pragma unroll
                for (int r = 0; r < 4; ++r) {
                    float gi = sigm(C[0][r] + be[s][0][r]);
                    float gf = sigm(C[1][r] + be[s][1][r]);
                    float gg = tanh_fast(C[2][r] + be[s][2][r]);
                    float go = sigm(C[3][r] + be[s][3][r]);
                    cst[s][r] = gf * cst[s][r] + gi * gg;
                    float h = go * tanh_fast(cst[s][r]);
                    hp4[r] = (_Float16)h;
                    if (r == 0) ho0 = h; else if (r == 1) ho1 = h;
                    else if (r == 2) ho2 = h; else ho3 = h;
                }
                // h -> Hb: ds_write_b64, units q*4..q*4+3 contiguous
                *(f16x4*)&Hb[pw][L][n][mh * 32 + s * 16 + q * 4] = hp4;
                if (L == 3) {
                    float4 st = make_float4(ho0, ho1, ho2, ho3);
                    *(float4*)(outp + (size_t)t * 64 + s * 16) = st;   // coalesced x4
                }
            }
        }
        // ---- raw barrier: drain LDS only; global loads/stores stay in flight ----
        __builtin_amdgcn_sched_barrier(0);
        asm volatile("s_waitcnt lgkmcnt(0)" ::: "memory");
        __builtin_amdgcn_s_barrier();
        __builtin_amdgcn_sched_barrier(0);
    }
}

extern "C" void kernel_launch(void* const* d_in, const int* in_sizes, int n_in,
                              void* d_out, int out_size, void* d_ws, size_t ws_size,
                              hipStream_t stream) {
    const float* x = (const float*)d_in[0];
    float* out = (float*)d_out;

    lstm_fused8<<<32, 512, 0, stream>>>(
        x, out,
        (const float*)d_in[1],  (const float*)d_in[2],
        (const float*)d_in[3],  (const float*)d_in[4],
        (const float*)d_in[5],  (const float*)d_in[6],
        (const float*)d_in[7],  (const float*)d_in[8],
        (const float*)d_in[9],  (const float*)d_in[10],
        (const float*)d_in[11], (const float*)d_in[12],
        (const float*)d_in[13], (const float*)d_in[14],
        (const float*)d_in[15], (const float*)d_in[16]);
}

// Round 6
// 450.372 us; speedup vs baseline: 1.2348x; 1.2348x over previous
//
#include <hip/hip_runtime.h>

// LSTM autoencoder: 4 layers 64->64, B=512, T=256 — fused, NO block barrier.
//
// 256 blocks x 512 threads (1 block/CU). Block = 2 batch elements x 4 layers.
// Wave w = (layer L = w>>1, unit-half mh = w&1) owns all 4 gates of units
// [mh*32, mh*32+32). Datapath identical to fused6 (best measured: 347us).
//
// ROUND-5 RESTRUCTURE: the per-tick __syncthreads/s_barrier lockstep is
// replaced by per-wave progress flags in LDS. Measured evidence: tick =
// ~3220 cy with a ~1500 cy serial skeleton constant across variants
// (barrier skew + ds_read latency + MFMA chain + Gs round trip + trans
// chain + drain) — waves in lockstep pay it serially. With flag sync,
// wave (L,mh) at step tau only waits for:
//   producers (layer L-1, both mh):  sigma >= tau      (v = h_{L-1}(tau))
//   pair      (L, mh^1):             sigma >= tau-1    (h_L(tau-1) other half)
//   consumers (layer L+1, both mh):  sigma >= tau-4    (4-slot h ring overwrite)
// so adjacent waves drift and their latency chains overlap (pipeline).
// h lives in a 4-slot ring Hb[slot=tau&3][layer][el][unit].
// Flag protocol: h ds_write -> s_waitcnt lgkmcnt(0) -> flag store (DS ops
// in-order per wave => consumers seeing the flag see the data). Polls use
// plain int2 LDS reads forced to re-load by an asm "memory" clobber.
// L0's x is prefetched one tick ahead into statically-named f32 regs.

typedef _Float16 f16x8 __attribute__((ext_vector_type(8)));
typedef float    f32x4 __attribute__((ext_vector_type(4)));

#define TSEQ 256

__device__ __forceinline__ float fast_rcp(float x) { return __builtin_amdgcn_rcpf(x); }
__device__ __forceinline__ float sigm(float x) { return fast_rcp(1.0f + __expf(-x)); }
__device__ __forceinline__ float tanh_fast(float x) {
    return 2.0f * fast_rcp(1.0f + __expf(-2.0f * x)) - 1.0f;
}
__device__ __forceinline__ f16x8 cvt8(float4 a, float4 b) {
    f16x8 f;
    f[0] = (_Float16)a.x; f[1] = (_Float16)a.y; f[2] = (_Float16)a.z; f[3] = (_Float16)a.w;
    f[4] = (_Float16)b.x; f[5] = (_Float16)b.y; f[6] = (_Float16)b.z; f[7] = (_Float16)b.w;
    return f;
}

__global__ __launch_bounds__(512, 2)
void lstm_fused9(const float* __restrict__ x,     // [512, 256, 64]
                 float* __restrict__ out,         // [512, 256, 64]
                 const float* __restrict__ Wih0, const float* __restrict__ Whh0,
                 const float* __restrict__ bi0,  const float* __restrict__ bh0,
                 const float* __restrict__ Wih1, const float* __restrict__ Whh1,
                 const float* __restrict__ bi1,  const float* __restrict__ bh1,
                 const float* __restrict__ Wih2, const float* __restrict__ Whh2,
                 const float* __restrict__ bi2,  const float* __restrict__ bh2,
                 const float* __restrict__ Wih3, const float* __restrict__ Whh3,
                 const float* __restrict__ bi3,  const float* __restrict__ bh3)
{
    __shared__ float    Gs[8 * 256];         // 8 KB: per-wave gate scratch
    __shared__ _Float16 Hb[4][4][2][64];     // 4 KB: slot ring, layer, el, unit
    __shared__ int      Sf[8];               // per-wave completed-step flags

    const int tid  = threadIdx.x;
    const int wave = tid >> 6;
    const int lane = tid & 63;
    const int L    = wave >> 1;     // layer 0..3
    const int mh   = wave & 1;      // unit-half: units [mh*32, mh*32+32)
    const int q    = lane >> 4;     // quad
    const int n    = lane & 15;     // MFMA col; valid batch cols are n<2
    const int b0   = blockIdx.x * 2;

    const float* Wih = (L == 0) ? Wih0 : (L == 1) ? Wih1 : (L == 2) ? Wih2 : Wih3;
    const float* Whh = (L == 0) ? Whh0 : (L == 1) ? Whh1 : (L == 2) ? Whh2 : Whh3;
    const float* bi  = (L == 0) ? bi0  : (L == 1) ? bi1  : (L == 2) ? bi2  : bi3;
    const float* bh  = (L == 0) ? bh0  : (L == 1) ? bh1  : (L == 2) ? bh2  : bh3;

    // ---- persistent A-fragments: tile (g,j) = rows g*64+mh*32+j*16+[0,16) ----
    f16x8 Aih[4][2][2], Ahh[4][2][2];
#pragma unroll
    for (int g = 0; g < 4; ++g) {
#pragma unroll
        for (int j = 0; j < 2; ++j) {
            const int row = g * 64 + mh * 32 + j * 16 + n;
#pragma unroll
            for (int c = 0; c < 2; ++c) {
                const float* pi = Wih + row * 64 + c * 32 + q * 8;
                const float* ph = Whh + row * 64 + c * 32 + q * 8;
                f16x8 fi, fh;
#pragma unroll
                for (int k = 0; k < 8; ++k) { fi[k] = (_Float16)pi[k]; fh[k] = (_Float16)ph[k]; }
                Aih[g][j][c] = fi;
                Ahh[g][j][c] = fh;
            }
        }
    }

    // ---- epilogue identity: lane owns (el = lane>>5, unit = mh*32+(lane&31)) ----
    const int eu = lane & 31;
    const int el = lane >> 5;
    const int unit = mh * 32 + eu;
    float4 be;
    be.x = bi[unit]       + bh[unit];
    be.y = bi[64 + unit]  + bh[64 + unit];
    be.z = bi[128 + unit] + bh[128 + unit];
    be.w = bi[192 + unit] + bh[192 + unit];
    float cst = 0.0f;
    float* outp = out + ((size_t)(b0 + el) * TSEQ) * 64 + unit;   // L==3 only

    // Gs addressing (compile-time-constant per lane)
    const int wo = wave * 256 + n * 128 + q * 4;
    const int ro = wave * 256 + el * 128 + (eu >> 4) * 64 + ((eu >> 2) & 3) * 4 + (eu & 3);

    // ---- zero h ring (all 4 slots): 4096 B = 1024 ints ----
    ((int*)Hb)[tid] = 0;
    ((int*)Hb)[tid + 512] = 0;
    if (tid < 8) Sf[tid] = -1;     // "completed step -1"

    // ---- L0 x prefetch: raw f32 one step ahead (lanes n<2 only; rest zero) ----
    const float* xbase = x + ((size_t)(b0 + (n & 1)) * TSEQ) * 64 + q * 8;
    float4 R0, R1, R2, R3;
    R0 = R1 = R2 = R3 = make_float4(0.f, 0.f, 0.f, 0.f);
    if (L == 0 && n < 2) {
        R0 = *(const float4*)(xbase);      R1 = *(const float4*)(xbase + 4);
        R2 = *(const float4*)(xbase + 32); R3 = *(const float4*)(xbase + 36);
    }

    __syncthreads();   // one-time: init visible to all waves

    const int prodBase = (L > 0) ? (2 * L - 2) : 0;        // even -> 8B aligned
    const int consBase = (L < 3) ? (2 * L + 2) : (2 * L);  // even -> 8B aligned

    for (int tau = 0; tau < TSEQ; ++tau) {
        const int sv = tau & 3;          // slot of h_{L-1}(tau); also my write slot
        const int sh = (tau - 1) & 3;    // slot of h_L(tau-1)
        const int fw = tau, fp = tau - 1, fb = tau - 4;

        // ---- poll: wait for producers / pair / consumers ----
        for (;;) {
            asm volatile("" ::: "memory");                 // force re-read of flags
            int2 P  = *(const int2*)&Sf[prodBase];         // layer L-1 pair
            int2 Q  = *(const int2*)&Sf[2 * L];            // my pair group
            int2 Rc = *(const int2*)&Sf[consBase];         // layer L+1 pair
            const int pairv = (mh == 0) ? Q.y : Q.x;
            bool ok;
            if (L == 0)      ok = (pairv >= fp) & (Rc.x >= fb) & (Rc.y >= fb);
            else if (L == 3) ok = (P.x >= fw) & (P.y >= fw) & (pairv >= fp);
            else             ok = (P.x >= fw) & (P.y >= fw) & (pairv >= fp)
                                 & (Rc.x >= fb) & (Rc.y >= fb);
            if (ok) break;
            __builtin_amdgcn_s_sleep(1);
        }

        // ---- input fragments ----
        f16x8 vf0, vf1;
        if (L == 0) {
            vf0 = cvt8(R0, R1);            // x(tau)
            vf1 = cvt8(R2, R3);
            if (tau + 1 < TSEQ && n < 2) { // prefetch x(tau+1)
                const float* p = xbase + (size_t)(tau + 1) * 64;
                R0 = *(const float4*)(p);      R1 = *(const float4*)(p + 4);
                R2 = *(const float4*)(p + 32); R3 = *(const float4*)(p + 36);
            }
        } else {
            const _Float16* vp = &Hb[sv][L - 1][n & 1][0];
            vf0 = *(const f16x8*)(vp + q * 8);
            vf1 = *(const f16x8*)(vp + 32 + q * 8);
        }
        const _Float16* hp = &Hb[sh][L][n & 1][0];
        f16x8 hf0 = *(const f16x8*)(hp + q * 8);
        f16x8 hf1 = *(const f16x8*)(hp + 32 + q * 8);

        const f32x4 z4 = {0.f, 0.f, 0.f, 0.f};

        // ---- 32 MFMA + direct C[g] f32x4 scatter (8 lanes write) ----
#pragma unroll
        for (int j = 0; j < 2; ++j) {
            f32x4 C[4];
#pragma unroll
            for (int g = 0; g < 4; ++g) {
                f32x4 c;
                c = __builtin_amdgcn_mfma_f32_16x16x32_f16(Ahh[g][j][0], hf0, z4, 0, 0, 0);
                c = __builtin_amdgcn_mfma_f32_16x16x32_f16(Ahh[g][j][1], hf1, c,  0, 0, 0);
                c = __builtin_amdgcn_mfma_f32_16x16x32_f16(Aih[g][j][0], vf0, c,  0, 0, 0);
                C[g] = __builtin_amdgcn_mfma_f32_16x16x32_f16(Aih[g][j][1], vf1, c, 0, 0, 0);
            }
            if (n < 2) {
#pragma unroll
                for (int g = 0; g < 4; ++g)
                    *(f32x4*)&Gs[wo + j * 64 + g * 16] = C[g];
            }
        }

        // ---- same-wave gather: 4 gates for this lane's (unit,el) ----
        float gvx = Gs[ro];
        float gvy = Gs[ro + 16];
        float gvz = Gs[ro + 32];
        float gvw = Gs[ro + 48];

        float gi = sigm(gvx + be.x);
        float gf = sigm(gvy + be.y);
        float gg = tanh_fast(gvz + be.z);
        float go = sigm(gvw + be.w);
        cst = gf * cst + gi * gg;
        float h = go * tanh_fast(cst);

        if (L == 3) outp[(size_t)tau * 64] = h;
        Hb[sv][L][el][unit] = (_Float16)h;

        // ---- publish: data-write drained, then flag (DS in-order per wave) ----
        asm volatile("s_waitcnt lgkmcnt(0)" ::: "memory");
        if (lane == 0) ((volatile int*)Sf)[wave] = tau;
    }
}

extern "C" void kernel_launch(void* const* d_in, const int* in_sizes, int n_in,
                              void* d_out, int out_size, void* d_ws, size_t ws_size,
                              hipStream_t stream) {
    const float* x = (const float*)d_in[0];
    float* out = (float*)d_out;

    lstm_fused9<<<256, 512, 0, stream>>>(
        x, out,
        (const float*)d_in[1],  (const float*)d_in[2],
        (const float*)d_in[3],  (const float*)d_in[4],
        (const float*)d_in[5],  (const float*)d_in[6],
        (const float*)d_in[7],  (const float*)d_in[8],
        (const float*)d_in[9],  (const float*)d_in[10],
        (const float*)d_in[11], (const float*)d_in[12],
        (const float*)d_in[13], (const float*)d_in[14],
        (const float*)d_in[15], (const float*)d_in[16]);
}